// Round 6
// baseline (263.359 us; speedup 1.0000x reference)
//
#include <hip/hip_runtime.h>
#include <stdint.h>

typedef unsigned short u16;
typedef unsigned int   u32;

#define NTOK   32768      // B*P
#define GD     768
#define GH     256
#define GH2    128
#define GE     64

typedef __bf16 bf16x8 __attribute__((ext_vector_type(8)));
typedef float  f32x4  __attribute__((ext_vector_type(4)));
union Frag { uint4 u; bf16x8 b; };

__device__ __forceinline__ float bf2f(u16 h) {
  union { u32 u; float f; } v; v.u = ((u32)h) << 16; return v.f;
}
__device__ __forceinline__ u16 f2bf(float f) {
  union { float f; u32 u; } v; v.f = f;
  u32 r = (v.u + 0x7fffu + ((v.u >> 16) & 1u)) >> 16;
  return (u16)r;
}

__device__ __forceinline__ void async16(void* lds, const void* g) {
  __builtin_amdgcn_global_load_lds(
      (const __attribute__((address_space(1))) void*)g,
      (__attribute__((address_space(3))) void*)lds, 16, 0, 0);
}

// raw barrier: drain LDS ops only (NOT vmcnt — keeps prefetch in flight)
__device__ __forceinline__ void bar_lds() {
  asm volatile("s_waitcnt lgkmcnt(0)" ::: "memory");
  __builtin_amdgcn_sched_barrier(0);
  __builtin_amdgcn_s_barrier();
  __builtin_amdgcn_sched_barrier(0);
}

__device__ __forceinline__ int getProp(const int* p32, int t, int is64) {
  return is64 ? p32[2 * t] : p32[t];
}

// ---------------- workspace layout (bytes) ----------------
// W1T/W2T stored PRE-TILED in LDS staging order:
//   W1T: [e][kt24][kgrp4][row256][kin8], W2T: [e][kt8][kgrp4][row128][kin8]
static const size_t OFF_W1T  = 0;            // bf16 64*256*768*2 = 25165824
static const size_t OFF_W2T  = 25165824;     // bf16 64*128*256*2 = 4194304
static const size_t OFF_TOK  = 29360128;     // int  NTOK*4 = 131072
static const size_t OFF_META = 29491200;     // ints (~46 KB)

// ---------------- K0: zero out + prop-dtype flag + per-block histogram -------
__global__ void setup_kernel(const int* __restrict__ prop, const float* __restrict__ mask,
                             u32* __restrict__ outz, int* __restrict__ counts2d,
                             int* __restrict__ cursors_p, int* __restrict__ flagp) {
  __shared__ int h[GE];
  __shared__ int vOr;
  const int b = blockIdx.x;                 // grid 128
  const int tid = threadIdx.x;
  outz[b * 512 + tid] = 0u;
  outz[b * 512 + 256 + tid] = 0u;
  if (b < 4) cursors_p[b * 256 + tid] = 0;
  if (tid < GE) h[tid] = 0;
  if (tid == 0) vOr = 0;
  __syncthreads();
  int v = prop[2 * tid + 1] | prop[2 * (tid + 256) + 1];
  if (v) atomicOr(&vOr, 1);
  __syncthreads();
  const int is64 = (vOr == 0) ? 1 : 0;
  if (b == 0 && tid == 0) *flagp = is64;
  const int t = b * 256 + tid;
  if (mask[t] > 0.f) atomicAdd(&h[getProp(prop, t, is64)], 1);
  __syncthreads();
  if (tid < GE) counts2d[b * GE + tid] = h[tid];
}

// ---------------- K1a: W1 fp32 [64][768][256] -> bf16 tiled -------------------
__global__ void transpose_w1(const float* __restrict__ in, u16* __restrict__ out) {
  __shared__ u16 tl[64][260];               // [h][d], 33.3 KB
  const int bid = blockIdx.x;               // grid 64*3*4 = 768
  const int e  = bid / 12, r = bid % 12;
  const int d0 = (r / 4) * 256, h0 = (r % 4) * 64;
  const int tid = threadIdx.x;
  const size_t inMat = (size_t)e * GD * GH;
  const size_t outMat = (size_t)e * GH * GD;
  const int h_l = (tid & 15) * 4, d_l = tid >> 4;
#pragma unroll
  for (int dd = 0; dd < 16; ++dd) {
    const int d = d_l + dd * 16;
    float4 v = *(const float4*)(in + inMat + (size_t)(d0 + d) * GH + h0 + h_l);
    tl[h_l + 0][d] = f2bf(v.x);
    tl[h_l + 1][d] = f2bf(v.y);
    tl[h_l + 2][d] = f2bf(v.z);
    tl[h_l + 3][d] = f2bf(v.w);
  }
  __syncthreads();
  const int wv = tid >> 6, ln = tid & 63;
  const int d_glob = d0 + ln * 4;
  const size_t tbase = outMat + (size_t)(d_glob >> 5) * 8192 +
                       (size_t)((d_glob >> 3) & 3) * 2048 + (d_glob & 7);
#pragma unroll
  for (int hh = 0; hh < 16; ++hh) {
    const int h = wv * 16 + hh;
    *(uint2*)(out + tbase + (size_t)(h0 + h) * 8) = *(const uint2*)&tl[h][ln * 4];
  }
}

// ---------------- K1b: W2 fp32 [E][256][128] -> bf16 tiled --------------------
__global__ void transpose_w2(const float* __restrict__ in, u16* __restrict__ out) {
  __shared__ u16 tile[32][33];
  const int tilesPerMat = 32;               // (256/32) * (128/32)
  const int e  = blockIdx.x / tilesPerMat;
  const int t  = blockIdx.x % tilesPerMat;
  const int tr = t / 4, tc = t % 4;         // tr: k-tile, tc: row-tile
  const size_t mat = (size_t)e * GH * GH2;
  const int tx = threadIdx.x & 31, ty = threadIdx.x >> 5;
  const int r0 = tr * 32, c0 = tc * 32;
#pragma unroll
  for (int i = 0; i < 32; i += 8)
    tile[ty + i][tx] = f2bf(in[mat + (size_t)(r0 + ty + i) * GH2 + c0 + tx]);
  __syncthreads();
  const int k = r0 + tx;
  const size_t kbase = mat + (size_t)(k >> 5) * 4096 +
                       (size_t)((k >> 3) & 3) * 1024 + (k & 7);
#pragma unroll
  for (int i = 0; i < 32; i += 8)
    out[kbase + (size_t)(c0 + ty + i) * 8] = tile[tx][ty + i];
}

// ---------------- K3: reduce counts2d + scan + tile table (128-row tiles) -----
__global__ void scan_kernel(const int* __restrict__ counts2d, int* __restrict__ offsets,
                            int* __restrict__ tileHead, int* __restrict__ tileRow,
                            int* __restrict__ nTilesPtr) {
  __shared__ int part[4][GE];
  const int tid = threadIdx.x;
  const int e = tid & 63, q = tid >> 6;
  int c = 0;
  for (int b = q * 32; b < q * 32 + 32; ++b) c += counts2d[b * GE + e];
  part[q][e] = c;
  __syncthreads();
  if (tid < GE) {
    const int ct = part[0][e] + part[1][e] + part[2][e] + part[3][e];
    int inc = ct;
#pragma unroll
    for (int d = 1; d < 64; d <<= 1) { int n = __shfl_up(inc, d); if (e >= d) inc += n; }
    const int off = inc - ct;
    offsets[e] = off;
    if (e == 63) offsets[64] = inc;
    int ntile = (ct + 127) >> 7;
    int inct = ntile;
#pragma unroll
    for (int d = 1; d < 64; d <<= 1) { int n = __shfl_up(inct, d); if (e >= d) inct += n; }
    const int tb = inct - ntile;
    for (int j = 0; j < ntile; ++j) { tileHead[tb + j] = e; tileRow[tb + j] = off + j * 128; }
    if (e == 63) *nTilesPtr = inct;
  }
}

// ---------------- K4: two-phase block scatter ---------------------------------
__global__ void scatter_kernel(const int* __restrict__ prop, const float* __restrict__ mask,
                               const int* __restrict__ offsets, int* __restrict__ cursors_p,
                               int* __restrict__ tokenIds, const int* __restrict__ flag) {
  __shared__ int h[GE];
  __shared__ int basebin[GE];
  const int tid = threadIdx.x;
  const int t = blockIdx.x * 256 + tid;  // grid 128
  if (tid < GE) h[tid] = 0;
  __syncthreads();
  int p = -1, rank = 0;
  if (mask[t] > 0.f) {
    p = getProp(prop, t, *flag);
    rank = atomicAdd(&h[p], 1);
  }
  __syncthreads();
  if (tid < GE && h[tid] > 0) basebin[tid] = atomicAdd(&cursors_p[tid * 16], h[tid]);
  __syncthreads();
  if (p >= 0) tokenIds[offsets[p] + basebin[p] + rank] = t;
}

// ---------------- K5: grouped fused LN + adapter GEMM -------------------------
// 128x256 tiles, 512 threads (8 waves, each 64x64 of GEMM1).
// B 4-buf (3-step slack) + pA 3-deep register prefetch; counted vmcnt(8/4/0);
// raw barriers. ~90 KB LDS -> 1 block/CU; ~232 blocks all resident.
__global__ __launch_bounds__(512, 1) void adapter_gemm(
    const float* __restrict__ hs, const u16* __restrict__ w1t, const u16* __restrict__ w2t,
    const float* __restrict__ lng, const float* __restrict__ lnb,
    const float* __restrict__ b1, const float* __restrict__ b2,
    const float* __restrict__ w3, const float* __restrict__ b3,
    const float* __restrict__ base, const float* __restrict__ mask,
    const int* __restrict__ tokenIds, const int* __restrict__ offsets,
    const int* __restrict__ tileHead, const int* __restrict__ tileRow,
    const int* __restrict__ nTilesPtr, float* __restrict__ outp) {
  __shared__ union LU {
    struct { u16 A[2][4096]; u16 B[4][8192]; } s;   // 80 KB staging
    u16 h[33792];                                   // h1 128x264 / h2 128x130
  } uni;
  __shared__ float sBias1[256];
  __shared__ float sBias2[128];
  __shared__ float sW3[2][128];
  __shared__ float sB3[2];
  __shared__ int   sTok[128];
  __shared__ __align__(16) float sGam[GD];
  __shared__ __align__(16) float sBet[GD];
  __shared__ float sMu[128];
  __shared__ float sRstd[128];

  const int tid  = threadIdx.x;                // 0..511
  const int wv   = tid >> 6;                   // 0..7
  const int wr   = wv >> 2;                    // row-half (0..1)
  const int wc   = wv & 3;                     // col-quarter (0..3)
  const int ln   = tid & 63;
  const int l15  = tid & 15;
  const int quad = (tid & 63) >> 4;
  const f32x4 vzero = {0.f, 0.f, 0.f, 0.f};
  const int nt = *nTilesPtr;
  const int qq = nt >> 3, rr = nt & 7;         // bijective XCD chunking

  for (int i = blockIdx.x; i < nt; i += gridDim.x) {
    const int x = i & 7, s = i >> 3;
    const int tile = (x < rr ? x * (qq + 1) : rr * (qq + 1) + (x - rr) * qq) + s;

    __syncthreads();  // tile top: full drain
    const int e  = tileHead[tile];
    const int rs = tileRow[tile];
    const int nRows = min(128, offsets[e + 1] - rs);

    if (tid < 128) sTok[tid] = tokenIds[rs + min(tid, nRows - 1)];
    if (tid < 256) sBias1[tid] = b1[e * GH + tid];
    if (tid < 128) sBias2[tid] = b2[e * GH2 + tid];
    if (tid < 256) { const int k = tid >> 1, o = tid & 1; sW3[o][k] = w3[e * GH2 * 2 + k * 2 + o]; }
    if (tid < 2) sB3[tid] = b3[e * 2 + tid];
    __syncthreads();

    const u16* w1e = w1t + (size_t)e * GH * GD;   // tiled [kt24][kgrp4][256][8]
    const u16* w2e = w2t + (size_t)e * GH2 * GH;  // tiled [kt8][kgrp4][128][8]

    // gamma/beta -> LDS (issued first: oldest vmem, retires first)
    if (tid < 192) {
      *(float4*)&sGam[tid * 4] = *(const float4*)(lng + (size_t)e * GD + tid * 4);
      *(float4*)&sBet[tid * 4] = *(const float4*)(lnb + (size_t)e * GD + tid * 4);
    }

    // per-thread A geometry: ONE row, 8 consecutive k per step
    const int r0x = tid >> 2;            // 0..127
    const int kg  = tid & 3;             // k-group in step
    const int kg8 = kg * 8;
    const float* xR = hs + (size_t)sTok[r0x] * GD + kg8;

#define ISSUE_PA(D, KT) do {                                                    \
    pA[D][0] = *(const float4*)(xR + (KT) * 32);                                \
    pA[D][1] = *(const float4*)(xR + (KT) * 32 + 4);                            \
  } while (0)

#define ISSUE_B(SB, KT) do {                                                    \
    u16* _bb = uni.s.B[SB] + wv * 1024;                                         \
    const u16* _gg = w1e + (KT) * 8192 + wv * 1024 + ln * 8;                    \
    async16(_bb, _gg); async16(_bb + 512, _gg + 512);                           \
  } while (0)

    float4 pA[3][2];
    // prologue: pA(0)/B(0) in flight during LN stats
    ISSUE_PA(0, 0);
    ISSUE_B(0, 0);
    __builtin_amdgcn_sched_barrier(0);

    // ---- LN stats: 16 lanes/row, 32 rows/pass, 4 passes ----
#pragma unroll 2
    for (int pass = 0; pass < 4; ++pass) {
      const int row = pass * 32 + (tid >> 4);
      const int l16 = tid & 15;
      const float* xp = hs + (size_t)sTok[row] * GD + l16 * 4;
      float sm = 0.f, sq = 0.f;
#pragma unroll
      for (int c = 0; c < 12; ++c) {
        float4 u = *(const float4*)(xp + c * 64);
        sm += u.x + u.y + u.z + u.w;
        sq += u.x*u.x + u.y*u.y + u.z*u.z + u.w*u.w;
      }
#pragma unroll
      for (int d = 1; d < 16; d <<= 1) { sm += __shfl_xor(sm, d); sq += __shfl_xor(sq, d); }
      if (l16 == 0) {
        const float mu = sm * (1.f / 768.f);
        sMu[row] = mu;
        sRstd[row] = rsqrtf(sq * (1.f / 768.f) - mu * mu + 1e-5f);
      }
    }
    // deepen pipeline after stats loads (stats retire before these)
    ISSUE_PA(1, 1);
    ISSUE_B(1, 1);
    ISSUE_PA(2, 2);
    ISSUE_B(2, 2);
    __builtin_amdgcn_sched_barrier(0);
    bar_lds();   // sMu/sRstd/sGam/sBet visible; prefetch NOT drained

    const float muR = sMu[r0x], rsR = sRstd[r0x];

#define XFORM_WRITE(PAR, D, K0) do {                                            \
    const float4 g0 = *(const float4*)&sGam[(K0) + kg8];                        \
    const float4 g1 = *(const float4*)&sGam[(K0) + kg8 + 4];                    \
    const float4 bb0 = *(const float4*)&sBet[(K0) + kg8];                       \
    const float4 bb1 = *(const float4*)&sBet[(K0) + kg8 + 4];                   \
    const float4 va = pA[D][0], vb = pA[D][1];                                  \
    uint4 o;                                                                    \
    o.x = (u32)f2bf((va.x - muR) * rsR * g0.x + bb0.x)                          \
        | ((u32)f2bf((va.y - muR) * rsR * g0.y + bb0.y) << 16);                 \
    o.y = (u32)f2bf((va.z - muR) * rsR * g0.z + bb0.z)                          \
        | ((u32)f2bf((va.w - muR) * rsR * g0.w + bb0.w) << 16);                 \
    o.z = (u32)f2bf((vb.x - muR) * rsR * g1.x + bb1.x)                          \
        | ((u32)f2bf((vb.y - muR) * rsR * g1.y + bb1.y) << 16);                 \
    o.w = (u32)f2bf((vb.z - muR) * rsR * g1.z + bb1.z)                          \
        | ((u32)f2bf((vb.w - muR) * rsR * g1.w + bb1.w) << 16);                 \
    *(uint4*)&uni.s.A[PAR][kg * 1024 + r0x * 8] = o;                            \
  } while (0)

    XFORM_WRITE(0, 0, 0);                           // A(0) -> buf 0
    asm volatile("s_waitcnt vmcnt(20)" ::: "memory");  // B(0) in LDS (allows B1/B2/pA1/pA2 + 12 stats)
    __builtin_amdgcn_sched_barrier(0);
    bar_lds();

    // ---- GEMM1: 24 k-steps, B 4-buf, pA 3-deep, counted vmcnt ----
    f32x4 acc1[4][4];
#pragma unroll
    for (int f = 0; f < 4; ++f)
#pragma unroll
      for (int g = 0; g < 4; ++g) acc1[f][g] = vzero;

#pragma unroll
    for (int kt = 0; kt < 24; ++kt) {
      Frag fa[4], fb[4];
#pragma unroll
      for (int f = 0; f < 4; ++f)
        fa[f].u = *(const uint4*)&uni.s.A[kt & 1][quad * 1024 + (wr * 64 + f * 16 + l15) * 8];
#pragma unroll
      for (int g = 0; g < 4; ++g)
        fb[g].u = *(const uint4*)&uni.s.B[kt & 3][quad * 2048 + (wc * 64 + g * 16 + l15) * 8];
      if (kt + 3 < 24) {
        ISSUE_PA((kt + 3) % 3, kt + 3);
        ISSUE_B((kt + 3) & 3, kt + 3);
        __builtin_amdgcn_sched_barrier(0);
      }
      __builtin_amdgcn_s_setprio(1);
#pragma unroll
      for (int f = 0; f < 4; ++f)
#pragma unroll
        for (int g = 0; g < 4; ++g)
          acc1[f][g] = __builtin_amdgcn_mfma_f32_16x16x32_bf16(fa[f].b, fb[g].b, acc1[f][g], 0, 0, 0);
      __builtin_amdgcn_s_setprio(0);
      if (kt + 1 < 24)
        XFORM_WRITE((kt + 1) & 1, (kt + 1) % 3, (kt + 1) * 32);
      if (kt <= 20) {
        asm volatile("s_waitcnt vmcnt(8)" ::: "memory");   // B(kt+1) landed
      } else if (kt == 21) {
        asm volatile("s_waitcnt vmcnt(4)" ::: "memory");
      } else if (kt == 22) {
        asm volatile("s_waitcnt vmcnt(0)" ::: "memory");
      }
      __builtin_amdgcn_sched_barrier(0);
      bar_lds();
    }

    // GEMM2 B -> registers (pre-tiled w2t; consumed reg-direct, no barriers)
    Frag bW2[8][2];
#pragma unroll
    for (int kt = 0; kt < 8; ++kt)
#pragma unroll
      for (int g = 0; g < 2; ++g)
        bW2[kt][g].u = *(const uint4*)(w2e + kt * 4096 + quad * 1024 +
                                       (size_t)(wc * 32 + g * 16 + l15) * 8);

    // epilogue 1: +b1, relu -> uni.h (stride 264)
#pragma unroll
    for (int f = 0; f < 4; ++f)
#pragma unroll
      for (int g = 0; g < 4; ++g) {
        const int col = wc * 64 + g * 16 + l15;
        const float bias = sBias1[col];
#pragma unroll
        for (int r = 0; r < 4; ++r) {
          const int row = wr * 64 + f * 16 + quad * 4 + r;
          uni.h[row * 264 + col] = f2bf(fmaxf(acc1[f][g][r] + bias, 0.f));
        }
      }
    bar_lds();   // h1 visible (bW2 loads stay in flight)

    // ---- GEMM2: h1[128x256] @ regB -> 128x128; no barriers ----
    f32x4 acc2[4][2];
#pragma unroll
    for (int f = 0; f < 4; ++f)
#pragma unroll
      for (int g = 0; g < 2; ++g) acc2[f][g] = vzero;

#pragma unroll
    for (int kt = 0; kt < 8; ++kt) {
      Frag fa2[4];
#pragma unroll
      for (int f = 0; f < 4; ++f)
        fa2[f].u = *(const uint4*)&uni.h[(wr * 64 + f * 16 + l15) * 264 + kt * 32 + quad * 8];
#pragma unroll
      for (int f = 0; f < 4; ++f)
#pragma unroll
        for (int g = 0; g < 2; ++g)
          acc2[f][g] = __builtin_amdgcn_mfma_f32_16x16x32_bf16(fa2[f].b, bW2[kt][g].b, acc2[f][g], 0, 0, 0);
    }
    bar_lds();   // all h1 reads done -> overwrite with h2

    // epilogue 2: +b2, relu -> uni.h as h2 (stride 130)
#pragma unroll
    for (int f = 0; f < 4; ++f)
#pragma unroll
      for (int g = 0; g < 2; ++g) {
        const int col = wc * 32 + g * 16 + l15;
        const float bias = sBias2[col];
#pragma unroll
        for (int r = 0; r < 4; ++r) {
          const int row = wr * 64 + f * 16 + quad * 4 + r;
          uni.h[row * 130 + col] = f2bf(fmaxf(acc2[f][g][r] + bias, 0.f));
        }
      }
    bar_lds();

    // ---------- GEMM3 + residual + mask + scatter-store (fp32) ----------
    // 512 threads: m = tid>>2, o = bit1, kh = bit0 (k-half), shfl combine
    {
      const int m = tid >> 2, o = (tid >> 1) & 1, kh = tid & 1;
      float a = (kh == 0) ? sB3[o] : 0.f;
      const u16* h2row = &uni.h[m * 130 + kh * 64];
      const float* w3row = &sW3[o][kh * 64];
#pragma unroll 16
      for (int k = 0; k < 64; ++k) a += bf2f(h2row[k]) * w3row[k];
      a += __shfl_xor(a, 1);
      if (kh == 0 && m < nRows) {
        const int t = sTok[m];
        const float mk = mask[t];
        const float bs = base[t * 2 + o];
        outp[t * 2 + o] = (0.7f * a + 0.3f * bs) * mk;
      }
    }
  }
#undef XFORM_WRITE
#undef ISSUE_PA
#undef ISSUE_B
}

extern "C" void kernel_launch(void* const* d_in, const int* in_sizes, int n_in,
                              void* d_out, int out_size, void* d_ws, size_t ws_size,
                              hipStream_t stream) {
  const float* hs   = (const float*)d_in[0];
  const float* base = (const float*)d_in[1];
  const int*   prop = (const int*)d_in[2];
  const float* mask = (const float*)d_in[3];
  const float* lng  = (const float*)d_in[4];
  const float* lnb  = (const float*)d_in[5];
  const float* W1   = (const float*)d_in[6];
  const float* b1   = (const float*)d_in[7];
  const float* W2   = (const float*)d_in[8];
  const float* b2   = (const float*)d_in[9];
  const float* W3   = (const float*)d_in[10];
  const float* b3   = (const float*)d_in[11];

  char* ws = (char*)d_ws;
  u16* w1t  = (u16*)(ws + OFF_W1T);
  u16* w2t  = (u16*)(ws + OFF_W2T);
  int* tok  = (int*)(ws + OFF_TOK);
  int* meta = (int*)(ws + OFF_META);
  int* counts2d  = meta;           // 8192 ints
  int* offsets   = meta + 8192;    // 65 ints
  int* tileHead  = meta + 8320;    // 1024 ints
  int* tileRow   = meta + 9344;    // 1024 ints
  int* nTiles    = meta + 10368;
  int* propFlag  = meta + 10369;
  int* cursors_p = meta + 10432;   // 1024 ints (64 bins, 64B-padded)

  setup_kernel<<<128, 256, 0, stream>>>(prop, mask, (u32*)d_out, counts2d,
                                        cursors_p, propFlag);
  transpose_w1<<<768, 256, 0, stream>>>(W1, w1t);
  transpose_w2<<<64 * 32, 256, 0, stream>>>(W2, w2t);
  scan_kernel<<<1, 256, 0, stream>>>(counts2d, offsets, tileHead, tileRow, nTiles);
  scatter_kernel<<<NTOK / 256, 256, 0, stream>>>(prop, mask, offsets, cursors_p, tok, propFlag);
  adapter_gemm<<<320, 512, 0, stream>>>(hs, w1t, w2t, lng, lnb, b1, b2, W3, b3,
                                        base, mask, tok, offsets, tileHead, tileRow,
                                        nTiles, (float*)d_out);
}

// Round 7
// 250.852 us; speedup vs baseline: 1.0499x; 1.0499x over previous
//
#include <hip/hip_runtime.h>
#include <stdint.h>

typedef unsigned short u16;
typedef unsigned int   u32;

#define NTOK   32768      // B*P
#define GD     768
#define GH     256
#define GH2    128
#define GE     64

typedef __bf16 bf16x8 __attribute__((ext_vector_type(8)));
typedef float  f32x4  __attribute__((ext_vector_type(4)));
union Frag { uint4 u; bf16x8 b; };

__device__ __forceinline__ float bf2f(u16 h) {
  union { u32 u; float f; } v; v.u = ((u32)h) << 16; return v.f;
}
__device__ __forceinline__ u16 f2bf(float f) {
  union { float f; u32 u; } v; v.f = f;
  u32 r = (v.u + 0x7fffu + ((v.u >> 16) & 1u)) >> 16;
  return (u16)r;
}

// raw barrier: drain LDS ops only (no global drain — B is in registers now)
__device__ __forceinline__ void bar_lds() {
  asm volatile("s_waitcnt lgkmcnt(0)" ::: "memory");
  __builtin_amdgcn_sched_barrier(0);
  __builtin_amdgcn_s_barrier();
  __builtin_amdgcn_sched_barrier(0);
}

__device__ __forceinline__ int getProp(const int* p32, int t, int is64) {
  return is64 ? p32[2 * t] : p32[t];
}

// ---------------- workspace layout (bytes) ----------------
// W1T/W2T stored PRE-TILED in the GEMM's fragment order:
//   W1T: [e][kt24][kgrp4][row256][kin8], W2T: [e][kt8][kgrp4][row128][kin8]
static const size_t OFF_W1T  = 0;            // bf16 64*256*768*2 = 25165824
static const size_t OFF_W2T  = 25165824;     // bf16 64*128*256*2 = 4194304
static const size_t OFF_TOK  = 29360128;     // int  NTOK*4 = 131072
static const size_t OFF_META = 29491200;     // ints (~46 KB)

// ---------------- K0: zero out + prop-dtype flag + per-block histogram -------
__global__ void setup_kernel(const int* __restrict__ prop, const float* __restrict__ mask,
                             u32* __restrict__ outz, int* __restrict__ counts2d,
                             int* __restrict__ cursors_p, int* __restrict__ flagp) {
  __shared__ int h[GE];
  __shared__ int vOr;
  const int b = blockIdx.x;                 // grid 128
  const int tid = threadIdx.x;
  outz[b * 512 + tid] = 0u;
  outz[b * 512 + 256 + tid] = 0u;
  if (b < 4) cursors_p[b * 256 + tid] = 0;
  if (tid < GE) h[tid] = 0;
  if (tid == 0) vOr = 0;
  __syncthreads();
  int v = prop[2 * tid + 1] | prop[2 * (tid + 256) + 1];
  if (v) atomicOr(&vOr, 1);
  __syncthreads();
  const int is64 = (vOr == 0) ? 1 : 0;
  if (b == 0 && tid == 0) *flagp = is64;
  const int t = b * 256 + tid;
  if (mask[t] > 0.f) atomicAdd(&h[getProp(prop, t, is64)], 1);
  __syncthreads();
  if (tid < GE) counts2d[b * GE + tid] = h[tid];
}

// ---------------- K1a: W1 fp32 [64][768][256] -> bf16 tiled -------------------
__global__ void transpose_w1(const float* __restrict__ in, u16* __restrict__ out) {
  __shared__ u16 tl[64][260];               // [h][d], 33.3 KB
  const int bid = blockIdx.x;               // grid 64*3*4 = 768
  const int e  = bid / 12, r = bid % 12;
  const int d0 = (r / 4) * 256, h0 = (r % 4) * 64;
  const int tid = threadIdx.x;
  const size_t inMat = (size_t)e * GD * GH;
  const size_t outMat = (size_t)e * GH * GD;
  const int h_l = (tid & 15) * 4, d_l = tid >> 4;
#pragma unroll
  for (int dd = 0; dd < 16; ++dd) {
    const int d = d_l + dd * 16;
    float4 v = *(const float4*)(in + inMat + (size_t)(d0 + d) * GH + h0 + h_l);
    tl[h_l + 0][d] = f2bf(v.x);
    tl[h_l + 1][d] = f2bf(v.y);
    tl[h_l + 2][d] = f2bf(v.z);
    tl[h_l + 3][d] = f2bf(v.w);
  }
  __syncthreads();
  const int wv = tid >> 6, ln = tid & 63;
  const int d_glob = d0 + ln * 4;
  const size_t tbase = outMat + (size_t)(d_glob >> 5) * 8192 +
                       (size_t)((d_glob >> 3) & 3) * 2048 + (d_glob & 7);
#pragma unroll
  for (int hh = 0; hh < 16; ++hh) {
    const int h = wv * 16 + hh;
    *(uint2*)(out + tbase + (size_t)(h0 + h) * 8) = *(const uint2*)&tl[h][ln * 4];
  }
}

// ---------------- K1b: W2 fp32 [E][256][128] -> bf16 tiled --------------------
__global__ void transpose_w2(const float* __restrict__ in, u16* __restrict__ out) {
  __shared__ u16 tile[32][33];
  const int tilesPerMat = 32;               // (256/32) * (128/32)
  const int e  = blockIdx.x / tilesPerMat;
  const int t  = blockIdx.x % tilesPerMat;
  const int tr = t / 4, tc = t % 4;         // tr: k-tile, tc: row-tile
  const size_t mat = (size_t)e * GH * GH2;
  const int tx = threadIdx.x & 31, ty = threadIdx.x >> 5;
  const int r0 = tr * 32, c0 = tc * 32;
#pragma unroll
  for (int i = 0; i < 32; i += 8)
    tile[ty + i][tx] = f2bf(in[mat + (size_t)(r0 + ty + i) * GH2 + c0 + tx]);
  __syncthreads();
  const int k = r0 + tx;
  const size_t kbase = mat + (size_t)(k >> 5) * 4096 +
                       (size_t)((k >> 3) & 3) * 1024 + (k & 7);
#pragma unroll
  for (int i = 0; i < 32; i += 8)
    out[kbase + (size_t)(c0 + ty + i) * 8] = tile[tx][ty + i];
}

// ---------------- K3: reduce counts2d + scan + tile table (64-row tiles) ------
__global__ void scan_kernel(const int* __restrict__ counts2d, int* __restrict__ offsets,
                            int* __restrict__ tileHead, int* __restrict__ tileRow,
                            int* __restrict__ nTilesPtr) {
  __shared__ int part[4][GE];
  const int tid = threadIdx.x;
  const int e = tid & 63, q = tid >> 6;
  int c = 0;
  for (int b = q * 32; b < q * 32 + 32; ++b) c += counts2d[b * GE + e];
  part[q][e] = c;
  __syncthreads();
  if (tid < GE) {
    const int ct = part[0][e] + part[1][e] + part[2][e] + part[3][e];
    int inc = ct;
#pragma unroll
    for (int d = 1; d < 64; d <<= 1) { int n = __shfl_up(inc, d); if (e >= d) inc += n; }
    const int off = inc - ct;
    offsets[e] = off;
    if (e == 63) offsets[64] = inc;
    int ntile = (ct + 63) >> 6;
    int inct = ntile;
#pragma unroll
    for (int d = 1; d < 64; d <<= 1) { int n = __shfl_up(inct, d); if (e >= d) inct += n; }
    const int tb = inct - ntile;
    for (int j = 0; j < ntile; ++j) { tileHead[tb + j] = e; tileRow[tb + j] = off + j * 64; }
    if (e == 63) *nTilesPtr = inct;
  }
}

// ---------------- K4: two-phase block scatter ---------------------------------
__global__ void scatter_kernel(const int* __restrict__ prop, const float* __restrict__ mask,
                               const int* __restrict__ offsets, int* __restrict__ cursors_p,
                               int* __restrict__ tokenIds, const int* __restrict__ flag) {
  __shared__ int h[GE];
  __shared__ int basebin[GE];
  const int tid = threadIdx.x;
  const int t = blockIdx.x * 256 + tid;  // grid 128
  if (tid < GE) h[tid] = 0;
  __syncthreads();
  int p = -1, rank = 0;
  if (mask[t] > 0.f) {
    p = getProp(prop, t, *flag);
    rank = atomicAdd(&h[p], 1);
  }
  __syncthreads();
  if (tid < GE && h[tid] > 0) basebin[tid] = atomicAdd(&cursors_p[tid * 16], h[tid]);
  __syncthreads();
  if (p >= 0) tokenIds[offsets[p] + basebin[p] + rank] = t;
}

// ---------------- K5: grouped fused LN + adapter GEMM -------------------------
// 64x256 tiles, 4 waves. B operand in per-wave REGISTERS (2-deep pipeline,
// compiler-managed waits) — no global_load_lds, no vmcnt at barriers; the
// per-step barrier orders only the A-tile ds_write->ds_read (2-step slack).
// LDS ~44 KB -> 3 blocks/CU.
__global__ __launch_bounds__(256, 2) void adapter_gemm(
    const float* __restrict__ hs, const u16* __restrict__ w1t, const u16* __restrict__ w2t,
    const float* __restrict__ lng, const float* __restrict__ lnb,
    const float* __restrict__ b1, const float* __restrict__ b2,
    const float* __restrict__ w3, const float* __restrict__ b3,
    const float* __restrict__ base, const float* __restrict__ mask,
    const int* __restrict__ tokenIds, const int* __restrict__ offsets,
    const int* __restrict__ tileHead, const int* __restrict__ tileRow,
    const int* __restrict__ nTilesPtr, float* __restrict__ outp) {
  __shared__ union LU {
    u16 A[3][2048];                                 // A staging 12 KB (3-buf)
    u16 h[17408];                                   // h1 stride 264 / h2 stride 130
  } uni;
  __shared__ float sBias1[256];
  __shared__ float sBias2[128];
  __shared__ float sW3[2][128];
  __shared__ float sB3[2];
  __shared__ int   sTok[64];
  __shared__ __align__(16) float sGam[GD];
  __shared__ __align__(16) float sBet[GD];
  __shared__ float sMu[64];
  __shared__ float sRstd[64];

  const int tid  = threadIdx.x;
  const int wv   = tid >> 6;
  const int l15  = tid & 15;
  const int quad = (tid & 63) >> 4;
  const f32x4 vzero = {0.f, 0.f, 0.f, 0.f};
  const int nt = *nTilesPtr;
  // bijective XCD chunking: consecutive tiles (same head) -> same XCD
  const int qq = nt >> 3, rr = nt & 7;

  for (int i = blockIdx.x; i < nt; i += gridDim.x) {
    const int x = i & 7, s = i >> 3;
    const int tile = (x < rr ? x * (qq + 1) : rr * (qq + 1) + (x - rr) * qq) + s;

    __syncthreads();  // tile top: full drain (prev tile's LDS reads done)
    const int e  = tileHead[tile];
    const int rs = tileRow[tile];
    const int nRows = min(64, offsets[e + 1] - rs);

    if (tid < 64) sTok[tid] = tokenIds[rs + min(tid, nRows - 1)];
    sBias1[tid] = b1[e * GH + tid];
    if (tid < 128) sBias2[tid] = b2[e * GH2 + tid];
    { const int k = tid >> 1, o = tid & 1; sW3[o][k] = w3[e * GH2 * 2 + k * 2 + o]; }
    if (tid < 2) sB3[tid] = b3[e * 2 + tid];
    __syncthreads();

    const u16* w1e = w1t + (size_t)e * GH * GD;   // tiled [kt24][kgrp4][256][8]
    const u16* w2e = w2t + (size_t)e * GH2 * GH;  // tiled [kt8][kgrp4][128][8]

    // gamma/beta -> LDS
    if (tid < 192) {
      *(float4*)&sGam[tid * 4] = *(const float4*)(lng + (size_t)e * GD + tid * 4);
      *(float4*)&sBet[tid * 4] = *(const float4*)(lnb + (size_t)e * GD + tid * 4);
    }

    // per-thread A geometry: rows (r0, r0+32), 4 consecutive k
    const int r0  = tid >> 3;            // 0..31
    const int klo = (tid & 7) * 4;       // 0,4,..,28
    const int kgrp = klo >> 3, kin = klo & 7;
    const float* xA = hs + (size_t)sTok[r0] * GD + klo;
    const float* xB = hs + (size_t)sTok[r0 + 32] * GD + klo;

    // ---- B register pipeline: per-wave quarter (cols wv*64..+63), 2-deep ----
    Frag fbE[4], fbO[4];   // even-kt / odd-kt slots
#define LOAD_FB(DST, KT) do {                                                   \
    const u16* _g = w1e + (KT) * 8192 + quad * 2048;                            \
    DST[0].u = *(const uint4*)(_g + (size_t)(wv * 64 +  0 + l15) * 8);          \
    DST[1].u = *(const uint4*)(_g + (size_t)(wv * 64 + 16 + l15) * 8);          \
    DST[2].u = *(const uint4*)(_g + (size_t)(wv * 64 + 32 + l15) * 8);          \
    DST[3].u = *(const uint4*)(_g + (size_t)(wv * 64 + 48 + l15) * 8);          \
  } while (0)

#define ISSUE_PA(D, KT) do {                                                    \
    pA[D][0] = *(const float4*)(xA + (KT) * 32);                                \
    pA[D][1] = *(const float4*)(xB + (KT) * 32);                                \
  } while (0)

    float4 pA[3][2];
    // prologue: pA(0..2) + B(0),B(1) in flight during LN stats
    ISSUE_PA(0, 0);
    ISSUE_PA(1, 1);
    ISSUE_PA(2, 2);
    LOAD_FB(fbE, 0);
    LOAD_FB(fbO, 1);
    __builtin_amdgcn_sched_barrier(0);

    // ---- LN stats: 16 lanes per row, 16 rows per pass, 4 passes ----
#pragma unroll 2
    for (int pass = 0; pass < 4; ++pass) {
      const int row = pass * 16 + (tid >> 4);
      const int l16 = tid & 15;
      const float* xp = hs + (size_t)sTok[row] * GD + l16 * 4;
      float sm = 0.f, sq = 0.f;
#pragma unroll
      for (int c = 0; c < 12; ++c) {
        float4 u = *(const float4*)(xp + c * 64);
        sm += u.x + u.y + u.z + u.w;
        sq += u.x*u.x + u.y*u.y + u.z*u.z + u.w*u.w;
      }
#pragma unroll
      for (int d = 1; d < 16; d <<= 1) { sm += __shfl_xor(sm, d); sq += __shfl_xor(sq, d); }
      if (l16 == 0) {
        const float mu = sm * (1.f / 768.f);
        sMu[row] = mu;
        sRstd[row] = rsqrtf(sq * (1.f / 768.f) - mu * mu + 1e-5f);
      }
    }
    bar_lds();   // sMu/sRstd/sGam/sBet visible; reg loads keep flying

    const float muA = sMu[r0],      rsA = sRstd[r0];
    const float muB = sMu[r0 + 32], rsB = sRstd[r0 + 32];

#define XFORM_WRITE(PAR, D, K0) do {                                            \
    const float4 gv = *(const float4*)&sGam[(K0) + klo];                        \
    const float4 bv = *(const float4*)&sBet[(K0) + klo];                        \
    const float4 va = pA[D][0], vb = pA[D][1];                                  \
    uint2 oa, ob;                                                               \
    oa.x = (u32)f2bf((va.x - muA) * rsA * gv.x + bv.x)                          \
         | ((u32)f2bf((va.y - muA) * rsA * gv.y + bv.y) << 16);                 \
    oa.y = (u32)f2bf((va.z - muA) * rsA * gv.z + bv.z)                          \
         | ((u32)f2bf((va.w - muA) * rsA * gv.w + bv.w) << 16);                 \
    ob.x = (u32)f2bf((vb.x - muB) * rsB * gv.x + bv.x)                          \
         | ((u32)f2bf((vb.y - muB) * rsB * gv.y + bv.y) << 16);                 \
    ob.y = (u32)f2bf((vb.z - muB) * rsB * gv.z + bv.z)                          \
         | ((u32)f2bf((vb.w - muB) * rsB * gv.w + bv.w) << 16);                 \
    *(uint2*)&uni.A[PAR][kgrp * 512 + r0 * 8 + kin] = oa;                       \
    *(uint2*)&uni.A[PAR][kgrp * 512 + (r0 + 32) * 8 + kin] = ob;                \
  } while (0)

    XFORM_WRITE(0, 0, 0);        // A(0) -> buf 0 (consumes pA slot 0)
    XFORM_WRITE(1, 1, 32);       // A(1) -> buf 1 (consumes pA slot 1)
    bar_lds();                   // bufs 0,1 ready

    // ---- GEMM1: 24 k-steps; B from regs, A from LDS (3-buf, write 2 ahead) ----
    f32x4 acc1[4][4];
#pragma unroll
    for (int f = 0; f < 4; ++f)
#pragma unroll
      for (int g = 0; g < 4; ++g) acc1[f][g] = vzero;

#pragma unroll
    for (int kt = 0; kt < 24; ++kt) {
      Frag fa[4];
#pragma unroll
      for (int f = 0; f < 4; ++f)
        fa[f].u = *(const uint4*)&uni.A[kt % 3][quad * 512 + (f * 16 + l15) * 8];
      if ((kt & 1) == 0) {
#pragma unroll
        for (int f = 0; f < 4; ++f)
#pragma unroll
          for (int g = 0; g < 4; ++g)
            acc1[f][g] = __builtin_amdgcn_mfma_f32_16x16x32_bf16(fa[f].b, fbE[g].b, acc1[f][g], 0, 0, 0);
        if (kt + 2 < 24) LOAD_FB(fbE, kt + 2);   // refill even slot (after use)
      } else {
#pragma unroll
        for (int f = 0; f < 4; ++f)
#pragma unroll
          for (int g = 0; g < 4; ++g)
            acc1[f][g] = __builtin_amdgcn_mfma_f32_16x16x32_bf16(fa[f].b, fbO[g].b, acc1[f][g], 0, 0, 0);
        if (kt + 2 < 24) LOAD_FB(fbO, kt + 2);   // refill odd slot (after use)
      }
      if (kt + 2 < 24)
        XFORM_WRITE((kt + 2) % 3, (kt + 2) % 3, (kt + 2) * 32);
      if (kt + 3 < 24)
        ISSUE_PA((kt + 3) % 3, kt + 3);
      bar_lds();   // orders A-writes(kt+2) vs A-reads; no global drain
    }
    bar_lds();   // A region fully read -> uni.h writable

    // GEMM2 B -> registers (pre-tiled w2t; consumed reg-direct, no barriers)
    Frag bW2[8][2];
#pragma unroll
    for (int kt = 0; kt < 8; ++kt)
#pragma unroll
      for (int g = 0; g < 2; ++g)
        bW2[kt][g].u = *(const uint4*)(w2e + kt * 4096 + quad * 1024 +
                                       (size_t)(wv * 32 + g * 16 + l15) * 8);

    // epilogue 1: +b1, relu -> uni.h (stride 264)
#pragma unroll
    for (int f = 0; f < 4; ++f)
#pragma unroll
      for (int g = 0; g < 4; ++g) {
        const int col = wv * 64 + g * 16 + l15;
        const float bias = sBias1[col];
#pragma unroll
        for (int r = 0; r < 4; ++r) {
          const int row = f * 16 + quad * 4 + r;
          uni.h[row * 264 + col] = f2bf(fmaxf(acc1[f][g][r] + bias, 0.f));
        }
      }
    bar_lds();   // h1 visible (bW2 loads stay in flight)

    // ---- GEMM2: h1[64x256] @ regB -> 64x128; no barriers ----
    f32x4 acc2[4][2];
#pragma unroll
    for (int f = 0; f < 4; ++f)
#pragma unroll
      for (int g = 0; g < 2; ++g) acc2[f][g] = vzero;

#pragma unroll
    for (int kt = 0; kt < 8; ++kt) {
      Frag fa2[4];
#pragma unroll
      for (int f = 0; f < 4; ++f)
        fa2[f].u = *(const uint4*)&uni.h[(f * 16 + l15) * 264 + kt * 32 + quad * 8];
#pragma unroll
      for (int f = 0; f < 4; ++f)
#pragma unroll
        for (int g = 0; g < 2; ++g)
          acc2[f][g] = __builtin_amdgcn_mfma_f32_16x16x32_bf16(fa2[f].b, bW2[kt][g].b, acc2[f][g], 0, 0, 0);
    }
    bar_lds();   // all h1 reads done -> overwrite with h2

    // epilogue 2: +b2, relu -> uni.h as h2 (stride 130)
#pragma unroll
    for (int f = 0; f < 4; ++f)
#pragma unroll
      for (int g = 0; g < 2; ++g) {
        const int col = wv * 32 + g * 16 + l15;
        const float bias = sBias2[col];
#pragma unroll
        for (int r = 0; r < 4; ++r) {
          const int row = f * 16 + quad * 4 + r;
          uni.h[row * 130 + col] = f2bf(fmaxf(acc2[f][g][r] + bias, 0.f));
        }
      }
    bar_lds();

    // ---------- GEMM3 + residual + mask + scatter-store (fp32) ----------
    const int m = tid >> 1, o = tid & 1;
    if (m < nRows) {
      float a = sB3[o];
      const u16* h2row = &uni.h[m * 130];
#pragma unroll 16
      for (int k = 0; k < 128; ++k) a += bf2f(h2row[k]) * sW3[o][k];
      const int t = sTok[m];
      const float mk = mask[t];
      const float bs = base[t * 2 + o];
      outp[t * 2 + o] = (0.7f * a + 0.3f * bs) * mk;
    }
  }
#undef XFORM_WRITE
#undef ISSUE_PA
#undef LOAD_FB
}

extern "C" void kernel_launch(void* const* d_in, const int* in_sizes, int n_in,
                              void* d_out, int out_size, void* d_ws, size_t ws_size,
                              hipStream_t stream) {
  const float* hs   = (const float*)d_in[0];
  const float* base = (const float*)d_in[1];
  const int*   prop = (const int*)d_in[2];
  const float* mask = (const float*)d_in[3];
  const float* lng  = (const float*)d_in[4];
  const float* lnb  = (const float*)d_in[5];
  const float* W1   = (const float*)d_in[6];
  const float* b1   = (const float*)d_in[7];
  const float* W2   = (const float*)d_in[8];
  const float* b2   = (const float*)d_in[9];
  const float* W3   = (const float*)d_in[10];
  const float* b3   = (const float*)d_in[11];

  char* ws = (char*)d_ws;
  u16* w1t  = (u16*)(ws + OFF_W1T);
  u16* w2t  = (u16*)(ws + OFF_W2T);
  int* tok  = (int*)(ws + OFF_TOK);
  int* meta = (int*)(ws + OFF_META);
  int* counts2d  = meta;           // 8192 ints
  int* offsets   = meta + 8192;    // 65 ints
  int* tileHead  = meta + 8320;    // 1024 ints
  int* tileRow   = meta + 9344;    // 1024 ints
  int* nTiles    = meta + 10368;
  int* propFlag  = meta + 10369;
  int* cursors_p = meta + 10432;   // 1024 ints (64 bins, 64B-padded)

  setup_kernel<<<128, 256, 0, stream>>>(prop, mask, (u32*)d_out, counts2d,
                                        cursors_p, propFlag);
  transpose_w1<<<768, 256, 0, stream>>>(W1, w1t);
  transpose_w2<<<64 * 32, 256, 0, stream>>>(W2, w2t);
  scan_kernel<<<1, 256, 0, stream>>>(counts2d, offsets, tileHead, tileRow, nTiles);
  scatter_kernel<<<NTOK / 256, 256, 0, stream>>>(prop, mask, offsets, cursors_p, tok, propFlag);
  adapter_gemm<<<640, 256, 0, stream>>>(hs, w1t, w2t, lng, lnb, b1, b2, W3, b3,
                                        base, mask, tok, offsets, tileHead, tileRow,
                                        nTiles, (float*)d_out);
}